// Round 10
// baseline (66.510 us; speedup 1.0000x reference)
//
#include <hip/hip_runtime.h>

// e = exp(-((x-cx)^2 w0^2 + ...)) with w' = w*sqrt(log2 e):
//   t_k = fma(x_k, w'_k, -c_k w'_k);  e = exp2(-(t0^2+t1^2+t2^2))
// du_k = -2 x1_k w_k^2 h e = t_k * (NEG_2LN2 * h * w'_k) * e
//
// R9: sparse kernel rebuilt — fused load+prefilter+COMPACT-RECORDS into LDS
// (no slist indirection in inner loop), 1-wave blocks, cells sub-chunked
// 4-ways for balance. Values deterministic: survivor set depends only on the
// fixed cell box, identical for every sub-chunk / intra-cell order.
typedef float v2f __attribute__((ext_vector_type(2)));

static constexpr float SQRT_LOG2E = 1.2011224087864498f;   // sqrt(log2(e))
static constexpr float NEG_2LN2   = -1.3862943611198906f;  // -2*ln(2)
static constexpr float S2_CUT     = 22.0f;                 // drop if smin >= 22 (log2 units)
#define NCELL 64                                           // 4x4x4
#define NSUB  4                                            // sub-chunks per cell

__device__ __forceinline__ v2f sp(float s) { return (v2f){s, s}; }
__device__ __forceinline__ v2f vfma(v2f a, v2f b, v2f c) {
    return __builtin_elementwise_fma(a, b, c);
}

__device__ __forceinline__ int cell_of(float a, float b, float c) {
    int cx = (int)(a * 4.f); cx = cx < 0 ? 0 : (cx > 3 ? 3 : cx);
    int cy = (int)(b * 4.f); cy = cy < 0 ? 0 : (cy > 3 ? 3 : cy);
    int cz = (int)(c * 4.f); cz = cz < 0 ? 0 : (cz > 3 ? 3 : cz);
    return cx + 4 * cy + 16 * cz;
}

// ---------------- tiny zero ----------------
__global__ __launch_bounds__(128) void zero_kernel(int* __restrict__ p) {
    p[threadIdx.x] = 0;    // hist[64] + gcur[64], contiguous
}

// ---------------- parallel counting sort ----------------
__global__ __launch_bounds__(256) void hist_kernel(
    const float* __restrict__ x, int* __restrict__ hist, int N)
{
    __shared__ int lh[NCELL];
    const int tid = threadIdx.x;
    if (tid < NCELL) lh[tid] = 0;
    __syncthreads();
    int i = blockIdx.x * 256 + tid;
    if (i < N) atomicAdd(&lh[cell_of(x[3 * i], x[3 * i + 1], x[3 * i + 2])], 1);
    __syncthreads();
    if (tid < NCELL && lh[tid]) atomicAdd(&hist[tid], lh[tid]);
}

__global__ __launch_bounds__(256) void scatter_kernel(
    const float* __restrict__ x, const int* __restrict__ hist, int* __restrict__ gcur,
    float* __restrict__ xs, float* __restrict__ ys, float* __restrict__ zs,
    int* __restrict__ iperm, int N)
{
    __shared__ int sexcl[NCELL], lcnt[NCELL], lbase[NCELL];
    const int tid = threadIdx.x;
    if (tid < 64) {                       // wave 0: global exclusive scan
        int hv = hist[tid], incl = hv;
        for (int o = 1; o < 64; o <<= 1) {
            int t = __shfl_up(incl, o);
            if (tid >= o) incl += t;
        }
        sexcl[tid] = incl - hv;
    } else if (tid < 128) {
        lcnt[tid - 64] = 0;
    }
    __syncthreads();
    const int i = blockIdx.x * 256 + tid;
    int cell = 0, r = 0; float a = 0.f, b = 0.f, c = 0.f;
    const bool ok = i < N;
    if (ok) {
        a = x[3 * i]; b = x[3 * i + 1]; c = x[3 * i + 2];
        cell = cell_of(a, b, c);
        r = atomicAdd(&lcnt[cell], 1);
    }
    __syncthreads();
    if (tid < 64) lbase[tid] = lcnt[tid] ? atomicAdd(&gcur[tid], lcnt[tid]) : 0;
    __syncthreads();
    if (ok) {
        int pos = sexcl[cell] + lbase[cell] + r;
        xs[pos] = a; ys[pos] = b; zs[pos] = c; iperm[i] = pos;
    }
}

// ---------------- main sparse kernel: 1 wave, compact records ----------------
template <int SET>  // 0: ux,uy,uz   1: P,Px   2: Q,Qy   3: R,Rz
__device__ __forceinline__ void srbf_cell_body(
    const float* __restrict__ xs, const float* __restrict__ ys,
    const float* __restrict__ zs,
    const float* __restrict__ h, const float* __restrict__ c,
    const float* __restrict__ w, const int* __restrict__ hist,
    float* __restrict__ dst, int N, int jbase, int jcount,
    float4* cA, float4* cB, float* cb2)
{
    constexpr int OB = (SET == 0) ? 0 : (2 * SET + 1);
    const int lane = threadIdx.x;

    // 64-wide scan of hist -> our cell's [start, count)
    int hv = hist[lane], incl = hv;
#pragma unroll
    for (int o = 1; o < 64; o <<= 1) {
        int t = __shfl_up(incl, o);
        if (lane >= o) incl += t;
    }
    const int excl   = incl - hv;
    const int cellid = blockIdx.x >> 2;          // NSUB=4
    const int sub    = blockIdx.x & (NSUB - 1);
    const int cstart = __shfl(excl, cellid);
    const int cpts   = __shfl(hv,  cellid);
    const int cend   = cstart + cpts;

    const float mid0 = ((cellid & 3) + 0.5f) * 0.25f;
    const float mid1 = (((cellid >> 2) & 3) + 0.5f) * 0.25f;
    const float mid2 = (((cellid >> 4) & 3) + 0.5f) * 0.25f;
    const float hf = 0.125f;

    // fused global-load + cell-box prefilter + compact-record store
    int cnt = 0;
    for (int j0 = 0; j0 < jcount; j0 += 64) {
        const int gj = jbase + j0 + lane;
        const float hj  = h[gj];
        const float w0  = w[3 * gj + 0] * SQRT_LOG2E;
        const float w1  = w[3 * gj + 1] * SQRT_LOG2E;
        const float w2  = w[3 * gj + 2] * SQRT_LOG2E;
        const float cw0 = -c[3 * gj + 0] * w0;
        const float cw1 = -c[3 * gj + 1] * w1;
        const float cw2 = -c[3 * gj + 2] * w2;
        const float v0  = fmaf(mid0, w0, cw0);
        const float v1  = fmaf(mid1, w1, cw1);
        const float v2_ = fmaf(mid2, w2, cw2);
        const float d0 = fmaxf(fabsf(v0)  - hf * w0, 0.f);
        const float d1 = fmaxf(fabsf(v1)  - hf * w1, 0.f);
        const float d2 = fmaxf(fabsf(v2_) - hf * w2, 0.f);
        const float smin = fmaf(d0, d0, fmaf(d1, d1, d2 * d2));
        const bool surv = smin < S2_CUT;
        unsigned long long m = __ballot(surv);
        const int pos = cnt + __popcll(m & ((1ull << lane) - 1ull));
        if (surv) {
            cA[pos] = make_float4(w0, w1, w2, cw0);
            if constexpr (SET == 0) {
                cB[pos]  = make_float4(cw1, cw2, NEG_2LN2 * hj * w0, NEG_2LN2 * hj * w1);
                cb2[pos] = NEG_2LN2 * hj * w2;
            } else {
                constexpr int K = SET - 1;
                const float wk = (K == 0) ? w0 : ((K == 1) ? w1 : w2);
                cB[pos] = make_float4(cw1, cw2, hj, NEG_2LN2 * hj * wk);
            }
        }
        cnt += __popcll(m);
    }
    __syncthreads();   // LDS writes visible before reads

    // point chunks: this sub-chunk + grid-stride (safety for huge cells)
    for (int p0 = cstart + sub * 256; p0 < cend; p0 += NSUB * 256) {
        int idx[4]; bool val[4];
#pragma unroll
        for (int g4 = 0; g4 < 4; ++g4) {
            int q = p0 + lane + 64 * g4;
            val[g4] = (q < cend);
            idx[g4] = val[g4] ? q : (cend - 1);
        }
        v2f px[2], py[2], pz[2];
        px[0] = (v2f){xs[idx[0]], xs[idx[1]]};
        py[0] = (v2f){ys[idx[0]], ys[idx[1]]};
        pz[0] = (v2f){zs[idx[0]], zs[idx[1]]};
        px[1] = (v2f){xs[idx[2]], xs[idx[3]]};
        py[1] = (v2f){ys[idx[2]], ys[idx[3]]};
        pz[1] = (v2f){zs[idx[2]], zs[idx[3]]};

        v2f a0[2] = {sp(0.f), sp(0.f)};
        v2f a1[2] = {sp(0.f), sp(0.f)};
        v2f a2[2] = {sp(0.f), sp(0.f)};

#pragma unroll 4
        for (int si = 0; si < cnt; ++si) {
            const float4 A = cA[si];   // w0,w1,w2,cw0   (unit-stride broadcast)
            const float4 B = cB[si];   // cw1,cw2,(b0|h),(b1|bk)
            float b2 = 0.f;
            if constexpr (SET == 0) b2 = cb2[si];
#pragma unroll
            for (int g = 0; g < 2; ++g) {
                v2f t0 = vfma(px[g], sp(A.x), sp(A.w));
                v2f t1 = vfma(py[g], sp(A.y), sp(B.x));
                v2f t2 = vfma(pz[g], sp(A.z), sp(B.y));
                v2f s  = vfma(t0, t0, vfma(t1, t1, t2 * t2));
                v2f e  = (v2f){__builtin_amdgcn_exp2f(-s.x),
                               __builtin_amdgcn_exp2f(-s.y)};
                if constexpr (SET == 0) {
                    a0[g] = vfma(t0, sp(B.z) * e, a0[g]);
                    a1[g] = vfma(t1, sp(B.w) * e, a1[g]);
                    a2[g] = vfma(t2, sp(b2)  * e, a2[g]);
                } else {
                    constexpr int K = SET - 1;
                    v2f tk = (K == 0) ? t0 : (K == 1 ? t1 : t2);
                    a0[g] = vfma(sp(B.z), e, a0[g]);
                    a1[g] = vfma(tk, sp(B.w) * e, a1[g]);
                }
            }
        }

        float r0[4] = {a0[0].x, a0[0].y, a0[1].x, a0[1].y};
        float r1[4] = {a1[0].x, a1[0].y, a1[1].x, a1[1].y};
        float r2[4] = {a2[0].x, a2[0].y, a2[1].x, a2[1].y};
#pragma unroll
        for (int g4 = 0; g4 < 4; ++g4) {
            if (!val[g4]) continue;
            int pos = p0 + lane + 64 * g4;
            dst[(OB + 0) * N + pos] = r0[g4];
            dst[(OB + 1) * N + pos] = r1[g4];
            if constexpr (SET == 0) dst[2 * N + pos] = r2[g4];
        }
    }
}

__global__ __launch_bounds__(64, 8) void srbf_cells(
    const float* xs, const float* ys, const float* zs,
    const float* h1, const float* c1, const float* w1,
    const float* h2, const float* c2, const float* w2,
    const float* h3, const float* c3, const float* w3,
    const float* h4, const float* c4, const float* w4,
    const int* hist, float* ws, int N, int jcount)
{
    extern __shared__ float lds[];
    float4* cA  = (float4*)lds;
    float4* cB  = cA + jcount;
    float*  cb2 = (float*)(cB + jcount);
    const int jbase = blockIdx.y * jcount;
    float* dst = ws + (size_t)blockIdx.y * 9 * N;
    switch (blockIdx.z) {
    case 0: srbf_cell_body<0>(xs, ys, zs, h1, c1, w1, hist, dst, N, jbase, jcount, cA, cB, cb2); break;
    case 1: srbf_cell_body<1>(xs, ys, zs, h2, c2, w2, hist, dst, N, jbase, jcount, cA, cB, cb2); break;
    case 2: srbf_cell_body<2>(xs, ys, zs, h3, c3, w3, hist, dst, N, jbase, jcount, cA, cB, cb2); break;
    case 3: srbf_cell_body<3>(xs, ys, zs, h4, c4, w4, hist, dst, N, jbase, jcount, cA, cB, cb2); break;
    }
}

__global__ __launch_bounds__(256) void reduce_gather(
    const float* __restrict__ ws, const int* __restrict__ iperm,
    float* __restrict__ out, int N, int split)
{
    const int i = blockIdx.x * 256 + threadIdx.x;   // original index: coalesced writes
    if (i < N) {
        const int pos = iperm[i];
#pragma unroll
        for (int row = 0; row < 9; ++row) {
            float acc = 0.f;
            for (int p = 0; p < split; ++p)
                acc += ws[((size_t)p * 9 + row) * N + pos];
            out[row * N + i] = acc;
        }
    }
}

// ---------------- dense fallback (R4) ----------------
template <int SET>
__device__ __forceinline__ void srbf_body_fb(
    const float* __restrict__ x, const float* __restrict__ h,
    const float* __restrict__ c, const float* __restrict__ w,
    float* __restrict__ dst, int N, int jbase, int jcount, float4* lds4)
{
    constexpr int OB = (SET == 0) ? 0 : (2 * SET + 1);
    const int tid = threadIdx.x;
    float* ldsb2 = (float*)(lds4 + 2 * jcount);
    for (int jj = tid; jj < jcount; jj += 256) {
        const int gj = jbase + jj;
        float hj  = h[gj];
        float w0  = w[3 * gj + 0] * SQRT_LOG2E;
        float w1  = w[3 * gj + 1] * SQRT_LOG2E;
        float w2  = w[3 * gj + 2] * SQRT_LOG2E;
        float cw0 = -c[3 * gj + 0] * w0;
        float cw1 = -c[3 * gj + 1] * w1;
        float cw2 = -c[3 * gj + 2] * w2;
        lds4[jj * 2 + 0] = make_float4(w0, w1, w2, cw0);
        if constexpr (SET == 0) {
            lds4[jj * 2 + 1] = make_float4(cw1, cw2, NEG_2LN2 * hj * w0, NEG_2LN2 * hj * w1);
            ldsb2[jj] = NEG_2LN2 * hj * w2;
        } else {
            constexpr int K = SET - 1;
            float wk = (K == 0) ? w0 : (K == 1 ? w1 : w2);
            lds4[jj * 2 + 1] = make_float4(cw1, cw2, hj, NEG_2LN2 * hj * wk);
        }
    }
    __syncthreads();
    const int i0 = blockIdx.x * 1024 + tid;
    v2f px[2], py[2], pz[2];
#pragma unroll
    for (int g = 0; g < 2; ++g) {
        const int ia = i0 + 512 * g, ib = ia + 256;
        px[g] = (v2f){x[3 * ia + 0], x[3 * ib + 0]};
        py[g] = (v2f){x[3 * ia + 1], x[3 * ib + 1]};
        pz[g] = (v2f){x[3 * ia + 2], x[3 * ib + 2]};
    }
    v2f a0[2] = {sp(0.f), sp(0.f)}, a1[2] = {sp(0.f), sp(0.f)}, a2[2] = {sp(0.f), sp(0.f)};
#pragma unroll 2
    for (int jj = 0; jj < jcount; ++jj) {
        const float4 A = lds4[jj * 2 + 0];
        const float4 B = lds4[jj * 2 + 1];
        float b2 = 0.f;
        if constexpr (SET == 0) b2 = ldsb2[jj];
#pragma unroll
        for (int g = 0; g < 2; ++g) {
            v2f t0 = vfma(px[g], sp(A.x), sp(A.w));
            v2f t1 = vfma(py[g], sp(A.y), sp(B.x));
            v2f t2 = vfma(pz[g], sp(A.z), sp(B.y));
            v2f s  = vfma(t0, t0, vfma(t1, t1, t2 * t2));
            v2f e  = (v2f){__builtin_amdgcn_exp2f(-s.x), __builtin_amdgcn_exp2f(-s.y)};
            if constexpr (SET == 0) {
                a0[g] = vfma(t0, sp(B.z) * e, a0[g]);
                a1[g] = vfma(t1, sp(B.w) * e, a1[g]);
                a2[g] = vfma(t2, sp(b2)  * e, a2[g]);
            } else {
                constexpr int K = SET - 1;
                v2f tk = (K == 0) ? t0 : (K == 1 ? t1 : t2);
                a0[g] = vfma(sp(B.z), e, a0[g]);
                a1[g] = vfma(tk, sp(B.w) * e, a1[g]);
            }
        }
    }
#pragma unroll
    for (int g = 0; g < 2; ++g) {
        const int ia = i0 + 512 * g, ib = ia + 256;
        dst[(OB + 0) * N + ia] = a0[g].x;  dst[(OB + 0) * N + ib] = a0[g].y;
        dst[(OB + 1) * N + ia] = a1[g].x;  dst[(OB + 1) * N + ib] = a1[g].y;
        if constexpr (SET == 0) { dst[2 * N + ia] = a2[g].x; dst[2 * N + ib] = a2[g].y; }
    }
}

__global__ __launch_bounds__(256, 8) void srbf_fallback(
    const float* x,
    const float* h1, const float* c1, const float* w1,
    const float* h2, const float* c2, const float* w2,
    const float* h3, const float* c3, const float* w3,
    const float* h4, const float* c4, const float* w4,
    float* out, float* ws, int N, int jcount, int split)
{
    extern __shared__ float ldsf[];
    float4* lds4 = (float4*)ldsf;
    const int jbase = blockIdx.y * jcount;
    float* dst = (split > 1) ? (ws + (size_t)blockIdx.y * 9 * N) : out;
    switch (blockIdx.z) {
    case 0: srbf_body_fb<0>(x, h1, c1, w1, dst, N, jbase, jcount, lds4); break;
    case 1: srbf_body_fb<1>(x, h2, c2, w2, dst, N, jbase, jcount, lds4); break;
    case 2: srbf_body_fb<2>(x, h3, c3, w3, dst, N, jbase, jcount, lds4); break;
    case 3: srbf_body_fb<3>(x, h4, c4, w4, dst, N, jbase, jcount, lds4); break;
    }
}

__global__ __launch_bounds__(256) void reduce_fb(
    const float4* __restrict__ ws, float4* __restrict__ out, int total4, int split)
{
    const int i = blockIdx.x * 256 + threadIdx.x;
    if (i < total4) {
        float4 acc = ws[i];
#pragma unroll 16
        for (int p = 1; p < split; ++p) {
            const float4 v = ws[(size_t)p * total4 + i];
            acc.x += v.x; acc.y += v.y; acc.z += v.z; acc.w += v.w;
        }
        out[i] = acc;
    }
}

// ---------------- launch ----------------
extern "C" void kernel_launch(void* const* d_in, const int* in_sizes, int n_in,
                              void* d_out, int out_size, void* d_ws, size_t ws_size,
                              hipStream_t stream)
{
    const float* x = (const float*)d_in[0];
    const int N  = in_sizes[0] / 3;   // 32768
    const int N1 = in_sizes[1];       // 1024
    float* out = (float*)d_out;
    float* wsf = (float*)d_ws;

    // ws floats: partials split*9N | xs N | ys N | zs N | iperm N | hist 64 | gcur 64
    int split = 0;
    {
        const int cand[3] = {8, 4, 2};
        for (int ci = 0; ci < 3; ++ci) {
            int s = cand[ci];
            if ((N1 % s) == 0 &&
                ws_size >= ((size_t)s * 9 * N + 4 * (size_t)N + 128) * 4) {
                split = s; break;
            }
        }
    }

    if (split) {
        size_t off = (size_t)split * 9 * N;
        float* xs  = wsf + off;
        float* ys  = xs + N;
        float* zs  = ys + N;
        int* iperm = (int*)(zs + N);
        int* hist  = iperm + N;
        // gcur = hist + 64 (zeroed together)

        zero_kernel<<<1, 128, 0, stream>>>(hist);
        const int nb = (N + 255) / 256;
        hist_kernel<<<nb, 256, 0, stream>>>(x, hist, N);
        scatter_kernel<<<nb, 256, 0, stream>>>(x, hist, hist + NCELL, xs, ys, zs, iperm, N);

        const int jcount = N1 / split;
        dim3 grid(NCELL * NSUB, split, 4);
        const size_t lds_bytes = (size_t)jcount * 36;
        srbf_cells<<<grid, 64, lds_bytes, stream>>>(
            xs, ys, zs,
            (const float*)d_in[1],  (const float*)d_in[2],  (const float*)d_in[3],
            (const float*)d_in[4],  (const float*)d_in[5],  (const float*)d_in[6],
            (const float*)d_in[7],  (const float*)d_in[8],  (const float*)d_in[9],
            (const float*)d_in[10], (const float*)d_in[11], (const float*)d_in[12],
            hist, wsf, N, jcount);

        reduce_gather<<<nb, 256, 0, stream>>>(wsf, iperm, out, N, split);
    } else {
        int fsplit = 1;
        for (int s = 16; s >= 2; s >>= 1) {
            if (ws_size >= (size_t)s * 9 * N * sizeof(float) && (N1 % s) == 0) {
                fsplit = s; break;
            }
        }
        const int jcount = N1 / fsplit;
        dim3 grid(N / 1024, fsplit, 4);
        const size_t lds_bytes = (size_t)jcount * (2 * sizeof(float4) + sizeof(float));
        srbf_fallback<<<grid, 256, lds_bytes, stream>>>(
            x,
            (const float*)d_in[1],  (const float*)d_in[2],  (const float*)d_in[3],
            (const float*)d_in[4],  (const float*)d_in[5],  (const float*)d_in[6],
            (const float*)d_in[7],  (const float*)d_in[8],  (const float*)d_in[9],
            (const float*)d_in[10], (const float*)d_in[11], (const float*)d_in[12],
            out, wsf, N, jcount, fsplit);
        if (fsplit > 1) {
            const int total4 = 9 * N / 4;
            reduce_fb<<<(total4 + 255) / 256, 256, 0, stream>>>(
                (const float4*)wsf, (float4*)out, total4, fsplit);
        }
    }
}

// Round 11
// 45.746 us; speedup vs baseline: 1.4539x; 1.4539x over previous
//
#include <hip/hip_runtime.h>

// e = exp(-((x-cx)^2 w0^2 + ...)) with w' = w*sqrt(log2 e):
//   t_k = fma(x_k, w'_k, -c_k w'_k);  e = exp2(-(t0^2+t1^2+t2^2))
// du_k = -2 x1_k w_k^2 h e = t_k * (NEG_2LN2 * h * w'_k) * e
//
// R10: (a) reduce reads made COALESCED (indexed by sorted pos; permutation
// moved to 9 scattered 4B writes), (b) NSUB=2 matching avg cell 512 pts,
// (c) early-exit before prefilter for point-less blocks.
typedef float v2f __attribute__((ext_vector_type(2)));

static constexpr float SQRT_LOG2E = 1.2011224087864498f;   // sqrt(log2(e))
static constexpr float NEG_2LN2   = -1.3862943611198906f;  // -2*ln(2)
static constexpr float S2_CUT     = 22.0f;                 // drop if smin >= 22 (log2 units)
#define NCELL 64                                           // 4x4x4
#define NSUB  2                                            // sub-chunks per cell

__device__ __forceinline__ v2f sp(float s) { return (v2f){s, s}; }
__device__ __forceinline__ v2f vfma(v2f a, v2f b, v2f c) {
    return __builtin_elementwise_fma(a, b, c);
}

__device__ __forceinline__ int cell_of(float a, float b, float c) {
    int cx = (int)(a * 4.f); cx = cx < 0 ? 0 : (cx > 3 ? 3 : cx);
    int cy = (int)(b * 4.f); cy = cy < 0 ? 0 : (cy > 3 ? 3 : cy);
    int cz = (int)(c * 4.f); cz = cz < 0 ? 0 : (cz > 3 ? 3 : cz);
    return cx + 4 * cy + 16 * cz;
}

// ---------------- tiny zero ----------------
__global__ __launch_bounds__(128) void zero_kernel(int* __restrict__ p) {
    p[threadIdx.x] = 0;    // hist[64] + gcur[64], contiguous
}

// ---------------- parallel counting sort ----------------
__global__ __launch_bounds__(256) void hist_kernel(
    const float* __restrict__ x, int* __restrict__ hist, int N)
{
    __shared__ int lh[NCELL];
    const int tid = threadIdx.x;
    if (tid < NCELL) lh[tid] = 0;
    __syncthreads();
    int i = blockIdx.x * 256 + tid;
    if (i < N) atomicAdd(&lh[cell_of(x[3 * i], x[3 * i + 1], x[3 * i + 2])], 1);
    __syncthreads();
    if (tid < NCELL && lh[tid]) atomicAdd(&hist[tid], lh[tid]);
}

__global__ __launch_bounds__(256) void scatter_kernel(
    const float* __restrict__ x, const int* __restrict__ hist, int* __restrict__ gcur,
    float* __restrict__ xs, float* __restrict__ ys, float* __restrict__ zs,
    int* __restrict__ perm, int N)
{
    __shared__ int sexcl[NCELL], lcnt[NCELL], lbase[NCELL];
    const int tid = threadIdx.x;
    if (tid < 64) {                       // wave 0: global exclusive scan
        int hv = hist[tid], incl = hv;
        for (int o = 1; o < 64; o <<= 1) {
            int t = __shfl_up(incl, o);
            if (tid >= o) incl += t;
        }
        sexcl[tid] = incl - hv;
    } else if (tid < 128) {
        lcnt[tid - 64] = 0;
    }
    __syncthreads();
    const int i = blockIdx.x * 256 + tid;
    int cell = 0, r = 0; float a = 0.f, b = 0.f, c = 0.f;
    const bool ok = i < N;
    if (ok) {
        a = x[3 * i]; b = x[3 * i + 1]; c = x[3 * i + 2];
        cell = cell_of(a, b, c);
        r = atomicAdd(&lcnt[cell], 1);
    }
    __syncthreads();
    if (tid < 64) lbase[tid] = lcnt[tid] ? atomicAdd(&gcur[tid], lcnt[tid]) : 0;
    __syncthreads();
    if (ok) {
        int pos = sexcl[cell] + lbase[cell] + r;
        xs[pos] = a; ys[pos] = b; zs[pos] = c;
        perm[pos] = i;                    // forward perm: sorted pos -> original i
    }
}

// ---------------- main sparse kernel: 1 wave, compact records ----------------
template <int SET>  // 0: ux,uy,uz   1: P,Px   2: Q,Qy   3: R,Rz
__device__ __forceinline__ void srbf_cell_body(
    const float* __restrict__ xs, const float* __restrict__ ys,
    const float* __restrict__ zs,
    const float* __restrict__ h, const float* __restrict__ c,
    const float* __restrict__ w, const int* __restrict__ hist,
    float* __restrict__ dst, int N, int jbase, int jcount,
    float4* cA, float4* cB, float* cb2)
{
    constexpr int OB = (SET == 0) ? 0 : (2 * SET + 1);
    const int lane = threadIdx.x;

    // 64-wide scan of hist -> our cell's [start, count)
    int hv = hist[lane], incl = hv;
#pragma unroll
    for (int o = 1; o < 64; o <<= 1) {
        int t = __shfl_up(incl, o);
        if (lane >= o) incl += t;
    }
    const int excl   = incl - hv;
    const int cellid = blockIdx.x >> 1;          // NSUB=2
    const int sub    = blockIdx.x & (NSUB - 1);
    const int cstart = __shfl(excl, cellid);
    const int cpts   = __shfl(hv,  cellid);
    const int cend   = cstart + cpts;

    if (cstart + sub * 256 >= cend) return;      // no points: skip prefilter too

    const float mid0 = ((cellid & 3) + 0.5f) * 0.25f;
    const float mid1 = (((cellid >> 2) & 3) + 0.5f) * 0.25f;
    const float mid2 = (((cellid >> 4) & 3) + 0.5f) * 0.25f;
    const float hf = 0.125f;

    // fused global-load + cell-box prefilter + compact-record store
    int cnt = 0;
    for (int j0 = 0; j0 < jcount; j0 += 64) {
        const int gj = jbase + j0 + lane;
        const float hj  = h[gj];
        const float w0  = w[3 * gj + 0] * SQRT_LOG2E;
        const float w1  = w[3 * gj + 1] * SQRT_LOG2E;
        const float w2  = w[3 * gj + 2] * SQRT_LOG2E;
        const float cw0 = -c[3 * gj + 0] * w0;
        const float cw1 = -c[3 * gj + 1] * w1;
        const float cw2 = -c[3 * gj + 2] * w2;
        const float v0  = fmaf(mid0, w0, cw0);
        const float v1  = fmaf(mid1, w1, cw1);
        const float v2_ = fmaf(mid2, w2, cw2);
        const float d0 = fmaxf(fabsf(v0)  - hf * w0, 0.f);
        const float d1 = fmaxf(fabsf(v1)  - hf * w1, 0.f);
        const float d2 = fmaxf(fabsf(v2_) - hf * w2, 0.f);
        const float smin = fmaf(d0, d0, fmaf(d1, d1, d2 * d2));
        const bool surv = smin < S2_CUT;
        unsigned long long m = __ballot(surv);
        const int pos = cnt + __popcll(m & ((1ull << lane) - 1ull));
        if (surv) {
            cA[pos] = make_float4(w0, w1, w2, cw0);
            if constexpr (SET == 0) {
                cB[pos]  = make_float4(cw1, cw2, NEG_2LN2 * hj * w0, NEG_2LN2 * hj * w1);
                cb2[pos] = NEG_2LN2 * hj * w2;
            } else {
                constexpr int K = SET - 1;
                const float wk = (K == 0) ? w0 : ((K == 1) ? w1 : w2);
                cB[pos] = make_float4(cw1, cw2, hj, NEG_2LN2 * hj * wk);
            }
        }
        cnt += __popcll(m);
    }
    __syncthreads();   // single wave: orders LDS writes before reads

    // point chunks: this sub-chunk + stride (for oversized cells)
    for (int p0 = cstart + sub * 256; p0 < cend; p0 += NSUB * 256) {
        int idx[4]; bool val[4];
#pragma unroll
        for (int g4 = 0; g4 < 4; ++g4) {
            int q = p0 + lane + 64 * g4;
            val[g4] = (q < cend);
            idx[g4] = val[g4] ? q : (cend - 1);
        }
        v2f px[2], py[2], pz[2];
        px[0] = (v2f){xs[idx[0]], xs[idx[1]]};
        py[0] = (v2f){ys[idx[0]], ys[idx[1]]};
        pz[0] = (v2f){zs[idx[0]], zs[idx[1]]};
        px[1] = (v2f){xs[idx[2]], xs[idx[3]]};
        py[1] = (v2f){ys[idx[2]], ys[idx[3]]};
        pz[1] = (v2f){zs[idx[2]], zs[idx[3]]};

        v2f a0[2] = {sp(0.f), sp(0.f)};
        v2f a1[2] = {sp(0.f), sp(0.f)};
        v2f a2[2] = {sp(0.f), sp(0.f)};

#pragma unroll 4
        for (int si = 0; si < cnt; ++si) {
            const float4 A = cA[si];   // w0,w1,w2,cw0   (unit-stride broadcast)
            const float4 B = cB[si];   // cw1,cw2,(b0|h),(b1|bk)
            float b2 = 0.f;
            if constexpr (SET == 0) b2 = cb2[si];
#pragma unroll
            for (int g = 0; g < 2; ++g) {
                v2f t0 = vfma(px[g], sp(A.x), sp(A.w));
                v2f t1 = vfma(py[g], sp(A.y), sp(B.x));
                v2f t2 = vfma(pz[g], sp(A.z), sp(B.y));
                v2f s  = vfma(t0, t0, vfma(t1, t1, t2 * t2));
                v2f e  = (v2f){__builtin_amdgcn_exp2f(-s.x),
                               __builtin_amdgcn_exp2f(-s.y)};
                if constexpr (SET == 0) {
                    a0[g] = vfma(t0, sp(B.z) * e, a0[g]);
                    a1[g] = vfma(t1, sp(B.w) * e, a1[g]);
                    a2[g] = vfma(t2, sp(b2)  * e, a2[g]);
                } else {
                    constexpr int K = SET - 1;
                    v2f tk = (K == 0) ? t0 : (K == 1 ? t1 : t2);
                    a0[g] = vfma(sp(B.z), e, a0[g]);
                    a1[g] = vfma(tk, sp(B.w) * e, a1[g]);
                }
            }
        }

        float r0[4] = {a0[0].x, a0[0].y, a0[1].x, a0[1].y};
        float r1[4] = {a1[0].x, a1[0].y, a1[1].x, a1[1].y};
        float r2[4] = {a2[0].x, a2[0].y, a2[1].x, a2[1].y};
#pragma unroll
        for (int g4 = 0; g4 < 4; ++g4) {
            if (!val[g4]) continue;
            int pos = p0 + lane + 64 * g4;
            dst[(OB + 0) * N + pos] = r0[g4];
            dst[(OB + 1) * N + pos] = r1[g4];
            if constexpr (SET == 0) dst[2 * N + pos] = r2[g4];
        }
    }
}

__global__ __launch_bounds__(64, 8) void srbf_cells(
    const float* xs, const float* ys, const float* zs,
    const float* h1, const float* c1, const float* w1,
    const float* h2, const float* c2, const float* w2,
    const float* h3, const float* c3, const float* w3,
    const float* h4, const float* c4, const float* w4,
    const int* hist, float* ws, int N, int jcount)
{
    extern __shared__ float lds[];
    float4* cA  = (float4*)lds;
    float4* cB  = cA + jcount;
    float*  cb2 = (float*)(cB + jcount);
    const int jbase = blockIdx.y * jcount;
    float* dst = ws + (size_t)blockIdx.y * 9 * N;
    switch (blockIdx.z) {
    case 0: srbf_cell_body<0>(xs, ys, zs, h1, c1, w1, hist, dst, N, jbase, jcount, cA, cB, cb2); break;
    case 1: srbf_cell_body<1>(xs, ys, zs, h2, c2, w2, hist, dst, N, jbase, jcount, cA, cB, cb2); break;
    case 2: srbf_cell_body<2>(xs, ys, zs, h3, c3, w3, hist, dst, N, jbase, jcount, cA, cB, cb2); break;
    case 3: srbf_cell_body<3>(xs, ys, zs, h4, c4, w4, hist, dst, N, jbase, jcount, cA, cB, cb2); break;
    }
}

// reduce indexed by SORTED pos: all ws reads coalesced; 9 scattered 4B writes.
__global__ __launch_bounds__(256) void reduce_perm(
    const float* __restrict__ ws, const int* __restrict__ perm,
    float* __restrict__ out, int N, int split)
{
    const int pos = blockIdx.x * 256 + threadIdx.x;
    if (pos < N) {
        const int op = perm[pos];
#pragma unroll
        for (int row = 0; row < 9; ++row) {
            float acc = 0.f;
#pragma unroll 8
            for (int p = 0; p < split; ++p)
                acc += ws[((size_t)p * 9 + row) * N + pos];
            out[row * N + op] = acc;
        }
    }
}

// ---------------- dense fallback (R4) ----------------
template <int SET>
__device__ __forceinline__ void srbf_body_fb(
    const float* __restrict__ x, const float* __restrict__ h,
    const float* __restrict__ c, const float* __restrict__ w,
    float* __restrict__ dst, int N, int jbase, int jcount, float4* lds4)
{
    constexpr int OB = (SET == 0) ? 0 : (2 * SET + 1);
    const int tid = threadIdx.x;
    float* ldsb2 = (float*)(lds4 + 2 * jcount);
    for (int jj = tid; jj < jcount; jj += 256) {
        const int gj = jbase + jj;
        float hj  = h[gj];
        float w0  = w[3 * gj + 0] * SQRT_LOG2E;
        float w1  = w[3 * gj + 1] * SQRT_LOG2E;
        float w2  = w[3 * gj + 2] * SQRT_LOG2E;
        float cw0 = -c[3 * gj + 0] * w0;
        float cw1 = -c[3 * gj + 1] * w1;
        float cw2 = -c[3 * gj + 2] * w2;
        lds4[jj * 2 + 0] = make_float4(w0, w1, w2, cw0);
        if constexpr (SET == 0) {
            lds4[jj * 2 + 1] = make_float4(cw1, cw2, NEG_2LN2 * hj * w0, NEG_2LN2 * hj * w1);
            ldsb2[jj] = NEG_2LN2 * hj * w2;
        } else {
            constexpr int K = SET - 1;
            float wk = (K == 0) ? w0 : (K == 1 ? w1 : w2);
            lds4[jj * 2 + 1] = make_float4(cw1, cw2, hj, NEG_2LN2 * hj * wk);
        }
    }
    __syncthreads();
    const int i0 = blockIdx.x * 1024 + tid;
    v2f px[2], py[2], pz[2];
#pragma unroll
    for (int g = 0; g < 2; ++g) {
        const int ia = i0 + 512 * g, ib = ia + 256;
        px[g] = (v2f){x[3 * ia + 0], x[3 * ib + 0]};
        py[g] = (v2f){x[3 * ia + 1], x[3 * ib + 1]};
        pz[g] = (v2f){x[3 * ia + 2], x[3 * ib + 2]};
    }
    v2f a0[2] = {sp(0.f), sp(0.f)}, a1[2] = {sp(0.f), sp(0.f)}, a2[2] = {sp(0.f), sp(0.f)};
#pragma unroll 2
    for (int jj = 0; jj < jcount; ++jj) {
        const float4 A = lds4[jj * 2 + 0];
        const float4 B = lds4[jj * 2 + 1];
        float b2 = 0.f;
        if constexpr (SET == 0) b2 = ldsb2[jj];
#pragma unroll
        for (int g = 0; g < 2; ++g) {
            v2f t0 = vfma(px[g], sp(A.x), sp(A.w));
            v2f t1 = vfma(py[g], sp(A.y), sp(B.x));
            v2f t2 = vfma(pz[g], sp(A.z), sp(B.y));
            v2f s  = vfma(t0, t0, vfma(t1, t1, t2 * t2));
            v2f e  = (v2f){__builtin_amdgcn_exp2f(-s.x), __builtin_amdgcn_exp2f(-s.y)};
            if constexpr (SET == 0) {
                a0[g] = vfma(t0, sp(B.z) * e, a0[g]);
                a1[g] = vfma(t1, sp(B.w) * e, a1[g]);
                a2[g] = vfma(t2, sp(b2)  * e, a2[g]);
            } else {
                constexpr int K = SET - 1;
                v2f tk = (K == 0) ? t0 : (K == 1 ? t1 : t2);
                a0[g] = vfma(sp(B.z), e, a0[g]);
                a1[g] = vfma(tk, sp(B.w) * e, a1[g]);
            }
        }
    }
#pragma unroll
    for (int g = 0; g < 2; ++g) {
        const int ia = i0 + 512 * g, ib = ia + 256;
        dst[(OB + 0) * N + ia] = a0[g].x;  dst[(OB + 0) * N + ib] = a0[g].y;
        dst[(OB + 1) * N + ia] = a1[g].x;  dst[(OB + 1) * N + ib] = a1[g].y;
        if constexpr (SET == 0) { dst[2 * N + ia] = a2[g].x; dst[2 * N + ib] = a2[g].y; }
    }
}

__global__ __launch_bounds__(256, 8) void srbf_fallback(
    const float* x,
    const float* h1, const float* c1, const float* w1,
    const float* h2, const float* c2, const float* w2,
    const float* h3, const float* c3, const float* w3,
    const float* h4, const float* c4, const float* w4,
    float* out, float* ws, int N, int jcount, int split)
{
    extern __shared__ float ldsf[];
    float4* lds4 = (float4*)ldsf;
    const int jbase = blockIdx.y * jcount;
    float* dst = (split > 1) ? (ws + (size_t)blockIdx.y * 9 * N) : out;
    switch (blockIdx.z) {
    case 0: srbf_body_fb<0>(x, h1, c1, w1, dst, N, jbase, jcount, lds4); break;
    case 1: srbf_body_fb<1>(x, h2, c2, w2, dst, N, jbase, jcount, lds4); break;
    case 2: srbf_body_fb<2>(x, h3, c3, w3, dst, N, jbase, jcount, lds4); break;
    case 3: srbf_body_fb<3>(x, h4, c4, w4, dst, N, jbase, jcount, lds4); break;
    }
}

__global__ __launch_bounds__(256) void reduce_fb(
    const float4* __restrict__ ws, float4* __restrict__ out, int total4, int split)
{
    const int i = blockIdx.x * 256 + threadIdx.x;
    if (i < total4) {
        float4 acc = ws[i];
#pragma unroll 16
        for (int p = 1; p < split; ++p) {
            const float4 v = ws[(size_t)p * total4 + i];
            acc.x += v.x; acc.y += v.y; acc.z += v.z; acc.w += v.w;
        }
        out[i] = acc;
    }
}

// ---------------- launch ----------------
extern "C" void kernel_launch(void* const* d_in, const int* in_sizes, int n_in,
                              void* d_out, int out_size, void* d_ws, size_t ws_size,
                              hipStream_t stream)
{
    const float* x = (const float*)d_in[0];
    const int N  = in_sizes[0] / 3;   // 32768
    const int N1 = in_sizes[1];       // 1024
    float* out = (float*)d_out;
    float* wsf = (float*)d_ws;

    // ws floats: partials split*9N | xs N | ys N | zs N | perm N | hist 64 | gcur 64
    int split = 0;
    {
        const int cand[3] = {8, 4, 2};
        for (int ci = 0; ci < 3; ++ci) {
            int s = cand[ci];
            if ((N1 % s) == 0 &&
                ws_size >= ((size_t)s * 9 * N + 4 * (size_t)N + 128) * 4) {
                split = s; break;
            }
        }
    }

    if (split) {
        size_t off = (size_t)split * 9 * N;
        float* xs  = wsf + off;
        float* ys  = xs + N;
        float* zs  = ys + N;
        int* perm  = (int*)(zs + N);
        int* hist  = perm + N;
        // gcur = hist + 64 (zeroed together)

        zero_kernel<<<1, 128, 0, stream>>>(hist);
        const int nb = (N + 255) / 256;
        hist_kernel<<<nb, 256, 0, stream>>>(x, hist, N);
        scatter_kernel<<<nb, 256, 0, stream>>>(x, hist, hist + NCELL, xs, ys, zs, perm, N);

        const int jcount = N1 / split;
        dim3 grid(NCELL * NSUB, split, 4);
        const size_t lds_bytes = (size_t)jcount * 36;
        srbf_cells<<<grid, 64, lds_bytes, stream>>>(
            xs, ys, zs,
            (const float*)d_in[1],  (const float*)d_in[2],  (const float*)d_in[3],
            (const float*)d_in[4],  (const float*)d_in[5],  (const float*)d_in[6],
            (const float*)d_in[7],  (const float*)d_in[8],  (const float*)d_in[9],
            (const float*)d_in[10], (const float*)d_in[11], (const float*)d_in[12],
            hist, wsf, N, jcount);

        reduce_perm<<<nb, 256, 0, stream>>>(wsf, perm, out, N, split);
    } else {
        int fsplit = 1;
        for (int s = 16; s >= 2; s >>= 1) {
            if (ws_size >= (size_t)s * 9 * N * sizeof(float) && (N1 % s) == 0) {
                fsplit = s; break;
            }
        }
        const int jcount = N1 / fsplit;
        dim3 grid(N / 1024, fsplit, 4);
        const size_t lds_bytes = (size_t)jcount * (2 * sizeof(float4) + sizeof(float));
        srbf_fallback<<<grid, 256, lds_bytes, stream>>>(
            x,
            (const float*)d_in[1],  (const float*)d_in[2],  (const float*)d_in[3],
            (const float*)d_in[4],  (const float*)d_in[5],  (const float*)d_in[6],
            (const float*)d_in[7],  (const float*)d_in[8],  (const float*)d_in[9],
            (const float*)d_in[10], (const float*)d_in[11], (const float*)d_in[12],
            out, wsf, N, jcount, fsplit);
        if (fsplit > 1) {
            const int total4 = 9 * N / 4;
            reduce_fb<<<(total4 + 255) / 256, 256, 0, stream>>>(
                (const float4*)wsf, (float4*)out, total4, fsplit);
        }
    }
}